// Round 23
// baseline (223.556 us; speedup 1.0000x reference)
//
#include <hip/hip_runtime.h>
#include <hip/hip_bf16.h>
#include <math.h>

#define D_   1024
#define H_   16
#define DH_  64
#define FFN_ 4096
#define B_   4
#define T_   1024
#define M_   128
#define N_   64
#define PREF 192
#define L_   1216
#define BL_  (B_*L_)   // 4864
#define BT_  (B_*T_)   // 4096

typedef __attribute__((ext_vector_type(4))) float f32x4;
typedef __attribute__((ext_vector_type(8))) short bf16x8;
typedef __attribute__((ext_vector_type(8))) unsigned short u16x8;
typedef const __attribute__((address_space(1))) void gvoid_t;
typedef __attribute__((address_space(3))) void lvoid_t;

#define LGKM0 asm volatile("s_waitcnt lgkmcnt(0)" ::: "memory")
#define CFENCE asm volatile("" ::: "memory")

__device__ __forceinline__ void gl_lds16(const void* g, void* l) {
    __builtin_amdgcn_global_load_lds((gvoid_t*)g, (lvoid_t*)l, 16, 0, 0);
}

__device__ __forceinline__ ushort f2bf(float x) {
    union { __hip_bfloat16 h; ushort u; } cv;
    cv.h = __float2bfloat16(x);
    return cv.u;
}

__device__ __forceinline__ float bf2f(ushort u) {
    union { unsigned int i; float f; } cv;
    cv.i = ((unsigned int)u) << 16;
    return cv.f;
}

__device__ __forceinline__ u16x8 pack8(float4 a, float4 b) {
    u16x8 r;
    r[0]=f2bf(a.x); r[1]=f2bf(a.y); r[2]=f2bf(a.z); r[3]=f2bf(a.w);
    r[4]=f2bf(b.x); r[5]=f2bf(b.y); r[6]=f2bf(b.z); r[7]=f2bf(b.w);
    return r;
}

// ---------------- block reduce helper ----------------
__device__ __forceinline__ float block_reduce_sum256(float v, float* sbuf) {
#pragma unroll
    for (int o = 32; o > 0; o >>= 1) v += __shfl_xor(v, o, 64);
    int w = threadIdx.x >> 6;
    if ((threadIdx.x & 63) == 0) sbuf[w] = v;
    __syncthreads();
    float r = sbuf[0] + sbuf[1] + sbuf[2] + sbuf[3];
    __syncthreads();
    return r;
}

// ---------------- weight fp32 [K][Nc] -> bf16 W^T [Nc][K] ----------------
__device__ __forceinline__ void wtr_body(const float* __restrict__ W,
                                         ushort* __restrict__ Wt, int K, int Nc)
{
    __shared__ float tl[64][65];
    int c0 = blockIdx.x << 6, k0 = blockIdx.y << 6;
    int tid = threadIdx.x;
    int rr = tid >> 4, c4 = (tid & 15) << 2;
#pragma unroll
    for (int p = 0; p < 4; ++p) {
        int r = (p << 4) + rr;
        float4 v = *(const float4*)(W + (size_t)(k0 + r) * Nc + c0 + c4);
        tl[r][c4+0] = v.x; tl[r][c4+1] = v.y; tl[r][c4+2] = v.z; tl[r][c4+3] = v.w;
    }
    __syncthreads();
#pragma unroll
    for (int p = 0; p < 4; ++p) {
        int rT = (p << 4) + rr;
        ushort4 uv;
        uv.x = f2bf(tl[c4+0][rT]);
        uv.y = f2bf(tl[c4+1][rT]);
        uv.z = f2bf(tl[c4+2][rT]);
        uv.w = f2bf(tl[c4+3][rT]);
        *(ushort4*)(Wt + (size_t)(c0 + rT) * K + k0 + c4) = uv;
    }
}

__global__ __launch_bounds__(256) void wtr_kernel(
    const float* __restrict__ W, ushort* __restrict__ Wt, int K, int Nc)
{ wtr_body(W, Wt, K, Nc); }

__global__ __launch_bounds__(256) void wtr4_kernel(
    const float* __restrict__ W0, const float* __restrict__ W1,
    const float* __restrict__ W2, const float* __restrict__ W3,
    ushort* __restrict__ T0, ushort* __restrict__ T1,
    ushort* __restrict__ T2, ushort* __restrict__ T3)
{
    const float* W; ushort* T;
    switch (blockIdx.z) {
        case 0: W = W0; T = T0; break;
        case 1: W = W1; T = T1; break;
        case 2: W = W2; T = T2; break;
        default: W = W3; T = T3; break;
    }
    wtr_body(W, T, D_, D_);
}

// ---------------- RoPE table + bias concat (merged prep) ------------------
__global__ __launch_bounds__(256) void prep_kernel(
    float* __restrict__ tab, const float* __restrict__ bq,
    const float* __restrict__ bk, const float* __restrict__ bv,
    float* __restrict__ ob)
{
    int i = blockIdx.x * 256 + threadIdx.x;
    if (i < L_ * 32) {
        int pos = i >> 5, idx = i & 31;
        int fi = idx & 15;
        float invf = exp2f(-(float)fi * 0.83048202372f);   // 10000^(-fi/16)
        float th = (float)pos * invf;
        tab[i] = (idx < 16) ? cosf(th) : sinf(th);
    } else {
        int j = i - L_ * 32;
        if (j < 3072) {
            float v = (j < 1024) ? bq[j] : (j < 2048 ? bk[j - 1024] : bv[j - 2048]);
            ob[j] = v;
        }
    }
}

// ---------------- concat + LayerNorm1: x_full f32, xa bf16 ----------------
__global__ __launch_bounds__(256) void ln1_concat_kernel(
    const float* __restrict__ x, const float* __restrict__ mem,
    const float* __restrict__ nmr, const float* __restrict__ g,
    const float* __restrict__ be, float* __restrict__ x_full,
    ushort* __restrict__ xa_bf)
{
    __shared__ float sbuf[4];
    int row = blockIdx.x;
    int b = row / L_, pos = row % L_;
    const float* src;
    if (pos < M_)          src = mem + ((size_t)b*M_ + pos)      * D_;
    else if (pos < M_+N_)  src = nmr + ((size_t)b*N_ + (pos-M_)) * D_;
    else                   src = x   + ((size_t)b*T_ + (pos-PREF))*D_;

    int c = threadIdx.x << 2;
    float4 v = *(const float4*)(src + c);
    float s = v.x + v.y + v.z + v.w;
    s = block_reduce_sum256(s, sbuf);
    float mu = s * (1.0f / D_);
    float dx = v.x - mu, dy = v.y - mu, dz = v.z - mu, dw = v.w - mu;
    float q = dx*dx + dy*dy + dz*dz + dw*dw;
    q = block_reduce_sum256(q, sbuf);
    float inv = rsqrtf(q * (1.0f / D_) + 1e-5f);
    float4 gv = *(const float4*)(g + c);
    float4 bv = *(const float4*)(be + c);
    ushort4 o;
    o.x = f2bf(dx*inv*gv.x + bv.x);
    o.y = f2bf(dy*inv*gv.y + bv.y);
    o.z = f2bf(dz*inv*gv.z + bv.z);
    o.w = f2bf(dw*inv*gv.w + bv.w);
    *(float4*)(x_full + (size_t)row*D_ + c) = v;
    *(ushort4*)(xa_bf + (size_t)row*D_ + c) = o;
}

// ---------------- LayerNorm2: f32 in, bf16 out ----------------------------
__global__ __launch_bounds__(256) void ln2_kernel(
    const float* __restrict__ src, const float* __restrict__ g,
    const float* __restrict__ be, ushort* __restrict__ dst)
{
    __shared__ float sbuf[4];
    int row = blockIdx.x;
    int c = threadIdx.x << 2;
    float4 v = *(const float4*)(src + (size_t)row*D_ + c);
    float s = v.x + v.y + v.z + v.w;
    s = block_reduce_sum256(s, sbuf);
    float mu = s * (1.0f / D_);
    float dx = v.x - mu, dy = v.y - mu, dz = v.z - mu, dw = v.w - mu;
    float q = dx*dx + dy*dy + dz*dz + dw*dw;
    q = block_reduce_sum256(q, sbuf);
    float inv = rsqrtf(q * (1.0f / D_) + 1e-5f);
    float4 gv = *(const float4*)(g + c);
    float4 bv = *(const float4*)(be + c);
    ushort4 o;
    o.x = f2bf(dx*inv*gv.x + bv.x);
    o.y = f2bf(dy*inv*gv.y + bv.y);
    o.z = f2bf(dz*inv*gv.z + bv.z);
    o.w = f2bf(dw*inv*gv.w + bv.w);
    *(ushort4*)(dst + (size_t)row*D_ + c) = o;
}

// ---------------- split-K=2 reduce (bf16 partials) + bias + res -> out ----
__global__ __launch_bounds__(256) void reduce2_out_kernel(
    const ushort* __restrict__ part, const float* __restrict__ b2,
    const float* __restrict__ x2, float* __restrict__ out)
{
    int row = blockIdx.x;
    int c = threadIdx.x << 2;
    size_t o = (size_t)row * D_ + c;
    const size_t S = (size_t)BT_ * D_;
    ushort4 u0 = *(const ushort4*)(part + o);
    ushort4 u1 = *(const ushort4*)(part + S + o);
    float4 bb = *(const float4*)(b2 + c);
    float4 rv = *(const float4*)(x2 + o);
    float4 v;
    v.x = bf2f(u0.x) + bf2f(u1.x) + bb.x + rv.x;
    v.y = bf2f(u0.y) + bf2f(u1.y) + bb.y + rv.y;
    v.z = bf2f(u0.z) + bf2f(u1.z) + bb.z + rv.z;
    v.w = bf2f(u0.w) + bf2f(u1.w) + bb.w + rv.w;
    *(float4*)(out + o) = v;
}

// ---------------- 512-thr GEMM: 128x256 tile, 3-slot, 1 barrier/iter ------
// MODE 3: relu(+bias)^2 bf16 out (FFN1).
// MODE 4: bf16 partial out at Cout + z*BT_*D_, kbase = z*Klen (FFN2 split-K).
// MODE 7: fused QKV epilogue (Q/K RoPE via table, V transposed head-major).
template<int MODE>
__global__ __launch_bounds__(512) void gemm_wide_kernel(
    const ushort* __restrict__ A, const ushort* __restrict__ Bt,
    const float* __restrict__ bias, const float* __restrict__ rtab,
    void* __restrict__ Cout, int Nc, int Kstride, int Klen)
{
    __shared__ ushort SM[36864];   // 72 KB: A 3x8KB | B 3x16KB
    char* SMb = (char*)SM;

    int tid = threadIdx.x;
    int lane = tid & 63, w = tid >> 6;
    int l15 = lane & 15, l4 = lane >> 4;

    int nx = gridDim.x;
    int flat = blockIdx.y * nx + blockIdx.x;
    int cpx = (nx * gridDim.y) >> 3;
    int sz = (flat & 7) * cpx + (flat >> 3);
    int row0 = (sz / nx) << 7, col0 = (sz % nx) << 8;
    int kbase = blockIdx.z * Klen;

    int wm = w >> 2, wn = w & 3;

    f32x4 acc[4][4] = {};

    int rA = tid >> 2, scA = tid & 3;
    int lcA = (scA ^ ((rA >> 1) & 3)) << 3;
    const ushort* Ar = A + (size_t)(row0 + rA) * Kstride + kbase + lcA;
    int lcB1 = (scA ^ (((128 + rA) >> 1) & 3)) << 3;
    const ushort* Br0 = Bt + (size_t)(col0 + rA)       * Kstride + kbase + lcA;
    const ushort* Br1 = Bt + (size_t)(col0 + 128 + rA) * Kstride + kbase + lcB1;

#define STG1(bb, k0rel)                                                       \
    do {                                                                      \
        gl_lds16(Ar  + (k0rel), SMb + (bb)*8192 + (tid << 4));                \
        gl_lds16(Br0 + (k0rel), SMb + 24576 + (bb)*16384 + (tid << 4));       \
        gl_lds16(Br1 + (k0rel), SMb + 24576 + (bb)*16384 + 8192 + (tid << 4));\
    } while (0)

    int nIt = Klen >> 5;
    STG1(0, 0);
    STG1(1, 32);
    int cur = 0;
    for (int it = 0; it < nIt; ++it) {
        if (it + 1 < nIt) {
            asm volatile("s_waitcnt vmcnt(3)" ::: "memory");
        } else {
            asm volatile("s_waitcnt vmcnt(0)" ::: "memory");
        }
        __builtin_amdgcn_s_barrier();
        CFENCE;
        if (it + 2 < nIt) {
            int s2 = cur + 2; if (s2 >= 3) s2 -= 3;
            STG1(s2, (it + 2) << 5);
        }
        const ushort* As = (const ushort*)(SMb + cur*8192);
        const ushort* Bs = (const ushort*)(SMb + 24576 + cur*16384);
        bf16x8 af[4], bfr[4];
#pragma unroll
        for (int i = 0; i < 4; ++i) {
            int ra = (wm << 6) + (i << 4) + l15;
            af[i]  = *(const bf16x8*)(&As[ra*32 + ((l4 ^ ((ra >> 1) & 3)) << 3)]);
            int rb = (wn << 6) + (i << 4) + l15;
            bfr[i] = *(const bf16x8*)(&Bs[rb*32 + ((l4 ^ ((rb >> 1) & 3)) << 3)]);
        }
#pragma unroll
        for (int i = 0; i < 4; ++i)
#pragma unroll
            for (int j = 0; j < 4; ++j)
                acc[i][j] = __builtin_amdgcn_mfma_f32_16x16x32_bf16(af[i], bfr[j], acc[i][j], 0, 0, 0);
        CFENCE;
        cur = (cur + 1 == 3) ? 0 : cur + 1;
    }
#undef STG1
    __syncthreads();   // drain reads before scratch aliases staging

    float bcol[4] = {0.f, 0.f, 0.f, 0.f};
    if (MODE != 4) {
#pragma unroll
        for (int j = 0; j < 4; ++j) bcol[j] = bias[col0 + (wn << 6) + (j << 4) + l15];
    }

    float* scr = (float*)SMb + w * 1088;   // aliases staging (dead)
    int rr = lane >> 2, cseg = lane & 3;
    int colbase = col0 + (wn << 6);
    int which = colbase >> 10;                // 0 Q, 1 K, 2 V (MODE 7)
    int hh = (colbase & 1023) >> 6;           // head (MODE 7)

#pragma unroll
    for (int i = 0; i < 4; ++i) {
        LGKM0;
#pragma unroll
        for (int j = 0; j < 4; ++j)
#pragma unroll
            for (int r = 0; r < 4; ++r) {
                float v = acc[i][j][r] + bcol[j];
                if (MODE == 3) { v = fmaxf(v, 0.f); v *= v; }
                scr[((l4 << 2) + r)*68 + (j << 4) + l15] = v;
            }
        LGKM0;
        int grow = row0 + (wm << 6) + (i << 4) + rr;

        if (MODE == 7 && which == 2) {
            // V^T: lane owns d = lane; 16 contiguous pos per chunk
            int r0g = row0 + (wm << 6) + (i << 4);
            int bb = r0g / L_;
            int posb = r0g - bb * L_;              // 16-aligned, never straddles
            float4 v0, v1, v2, v3;
            v0.x = scr[ 0*68 + lane]; v0.y = scr[ 1*68 + lane];
            v0.z = scr[ 2*68 + lane]; v0.w = scr[ 3*68 + lane];
            v1.x = scr[ 4*68 + lane]; v1.y = scr[ 5*68 + lane];
            v1.z = scr[ 6*68 + lane]; v1.w = scr[ 7*68 + lane];
            v2.x = scr[ 8*68 + lane]; v2.y = scr[ 9*68 + lane];
            v2.z = scr[10*68 + lane]; v2.w = scr[11*68 + lane];
            v3.x = scr[12*68 + lane]; v3.y = scr[13*68 + lane];
            v3.z = scr[14*68 + lane]; v3.w = scr[15*68 + lane];
            ushort* O = (ushort*)Cout + 2*(size_t)BL_*D_;
            size_t base = ((size_t)(bb*H_ + hh)*64 + lane)*L_ + posb;
            *(u16x8*)(O + base)     = pack8(v0, v1);
            *(u16x8*)(O + base + 8) = pack8(v2, v3);
        } else if (MODE == 7) {
            // Q/K: lane owns one pos row, 16 cols; RoPE from table
            int bb = grow / L_;
            int pos = grow - bb * L_;
            float4 a0 = *(float4*)&scr[rr*68 + (cseg << 4) + 0];
            float4 a1 = *(float4*)&scr[rr*68 + (cseg << 4) + 4];
            float4 a2 = *(float4*)&scr[rr*68 + (cseg << 4) + 8];
            float4 a3 = *(float4*)&scr[rr*68 + (cseg << 4) + 12];
            if (cseg < 2) {
                int oseg = cseg ^ 1;
                float4 p0 = *(float4*)&scr[rr*68 + (oseg << 4) + 0];
                float4 p1 = *(float4*)&scr[rr*68 + (oseg << 4) + 4];
                float4 p2 = *(float4*)&scr[rr*68 + (oseg << 4) + 8];
                float4 p3 = *(float4*)&scr[rr*68 + (oseg << 4) + 12];
                const float* tb = rtab + pos*32;
                float4 c0 = *(const float4*)(tb + 0),  c1 = *(const float4*)(tb + 4);
                float4 c2 = *(const float4*)(tb + 8),  c3 = *(const float4*)(tb + 12);
                float4 s0 = *(const float4*)(tb + 16), s1 = *(const float4*)(tb + 20);
                float4 s2 = *(const float4*)(tb + 24), s3 = *(const float4*)(tb + 28);
                float sg = (cseg == 0) ? -1.f : 1.f;
                a0.x = a0.x*c0.x + sg*p0.x*s0.x; a0.y = a0.y*c0.y + sg*p0.y*s0.y;
                a0.z = a0.z*c0.z + sg*p0.z*s0.z; a0.w = a0.w*c0.w + sg*p0.w*s0.w;
                a1.x = a1.x*c1.x + sg*p1.x*s1.x; a1.y = a1.y*c1.y + sg*p1.y*s1.y;
                a1.z = a1.z*c1.z + sg*p1.z*s1.z; a1.w = a1.w*c1.w + sg*p1.w*s1.w;
                a2.x = a2.x*c2.x + sg*p2.x*s2.x; a2.y = a2.y*c2.y + sg*p2.y*s2.y;
                a2.z = a2.z*c2.z + sg*p2.z*s2.z; a2.w = a2.w*c2.w + sg*p2.w*s2.w;
                a3.x = a3.x*c3.x + sg*p3.x*s3.x; a3.y = a3.y*c3.y + sg*p3.y*s3.y;
                a3.z = a3.z*c3.z + sg*p3.z*s3.z; a3.w = a3.w*c3.w + sg*p3.w*s3.w;
            }
            ushort* O = (ushort*)Cout + (size_t)which * ((size_t)BL_*D_);
            size_t base = (((size_t)(bb*H_ + hh)*L_ + pos) << 6) + (cseg << 4);
            *(u16x8*)(O + base)     = pack8(a0, a1);
            *(u16x8*)(O + base + 8) = pack8(a2, a3);
        } else {
            float4 q0 = *(float4*)&scr[rr*68 + (cseg << 4) + 0];
            float4 q1 = *(float4*)&scr[rr*68 + (cseg << 4) + 4];
            float4 q2 = *(float4*)&scr[rr*68 + (cseg << 4) + 8];
            float4 q3 = *(float4*)&scr[rr*68 + (cseg << 4) + 12];
            int gcol = colbase + (cseg << 4);
            if (MODE == 3) {
                ushort* O = (ushort*)Cout;
                *(u16x8*)(O + (size_t)grow*Nc + gcol)     = pack8(q0, q1);
                *(u16x8*)(O + (size_t)grow*Nc + gcol + 8) = pack8(q2, q3);
            } else {
                // bf16 partials (halves split-K HBM traffic)
                ushort* O = (ushort*)Cout + (size_t)blockIdx.z * ((size_t)BT_ * D_);
                size_t o = (size_t)grow*Nc + gcol;
                *(u16x8*)(O + o)     = pack8(q0, q1);
                *(u16x8*)(O + o + 8) = pack8(q2, q3);
            }
        }
    }
}

// ---------------- 256-thr GEMM: 128x64 tile, in-block split-K=2 -----------
// 3-slot pipeline per group, single barrier/iter, vmcnt(6)/0.
// modes: 1 f32 +bias +res(row-major) | 2 f32 +bias +res(strided x_full)
__global__ __launch_bounds__(256) void gemm_sk2_kernel(
    const ushort* __restrict__ A, const ushort* __restrict__ Bt,
    const float* __restrict__ bias, const float* __restrict__ res,
    float* __restrict__ Cout, int Nc, int Kstride, int Klen, int mode)
{
    __shared__ ushort SM[36864];   // 72 KB
    char* SMb = (char*)SM;
    int tid = threadIdx.x;
    int lane = tid & 63, w = tid >> 6;
    int l15 = lane & 15, l4 = lane >> 4;
    int g = w >> 1, wm = w & 1;

    int nx = gridDim.x;
    int flat = blockIdx.y * nx + blockIdx.x;
    int cpx = (nx * gridDim.y) >> 3;
    int sz = (flat & 7) * cpx + (flat >> 3);
    int row0 = (sz / nx) << 7, col0 = (sz % nx) << 6;

    f32x4 acc[4][4] = {};
    const int kl = Klen >> 1;
    const int kb = g * kl;

    int gt = tid & 127;
    int rB = gt >> 2, sc = gt & 3;
    const ushort* Abase = A  + (size_t)row0 * Kstride + kb;
    const ushort* Bbase = Bt + (size_t)col0 * Kstride + kb;
    char* ALg = SMb + g * 24576;             // 3 bufs x 8KB
    char* BLg = SMb + 49152 + g * 12288;     // 3 bufs x 4KB

#define STG2(bb, k0rel)                                                       \
    do {                                                                      \
        _Pragma("unroll")                                                     \
        for (int p = 0; p < 4; ++p) {                                         \
            int rw = (p << 5) + rB; int lc = sc ^ ((rw >> 1) & 3);            \
            gl_lds16(Abase + (size_t)rw*Kstride + (k0rel) + (lc << 3),        \
                     ALg + (bb)*8192 + (p << 11) + (gt << 4));                \
        }                                                                     \
        _Pragma("unroll")                                                     \
        for (int p = 0; p < 2; ++p) {                                         \
            int rw = (p << 5) + rB; int lc = sc ^ ((rw >> 1) & 3);            \
            gl_lds16(Bbase + (size_t)rw*Kstride + (k0rel) + (lc << 3),        \
                     BLg + (bb)*4096 + (p << 11) + (gt << 4));                \
        }                                                                     \
    } while (0)

    int nIt = kl >> 5;
    STG2(0, 0);
    STG2(1, 32);
    int cur = 0;
    for (int it = 0; it < nIt; ++it) {
        if (it + 1 < nIt) {
            asm volatile("s_waitcnt vmcnt(6)" ::: "memory");
        } else {
            asm volatile("s_waitcnt vmcnt(0)" ::: "memory");
        }
        __builtin_amdgcn_s_barrier();
        CFENCE;
        if (it + 2 < nIt) {
            int s2 = cur + 2; if (s2 >= 3) s2 -= 3;
            STG2(s2, (it + 2) << 5);
        }
        const ushort* As = (const ushort*)(ALg + cur*8192);
        const ushort* Bs = (const ushort*)(BLg + cur*4096);
        bf16x8 af[4], bfr[4];
#pragma unroll
        for (int i = 0; i < 4; ++i) {
            int ra = (wm << 6) + (i << 4) + l15;
            af[i]  = *(const bf16x8*)(&As[ra*32 + ((l4 ^ ((ra >> 1) & 3)) << 3)]);
            int rb = (i << 4) + l15;
            bfr[i] = *(const bf16x8*)(&Bs[rb*32 + ((l4 ^ ((rb >> 1) & 3)) << 3)]);
        }
#pragma unroll
        for (int i = 0; i < 4; ++i)
#pragma unroll
            for (int j = 0; j < 4; ++j)
                acc[i][j] = __builtin_amdgcn_mfma_f32_16x16x32_bf16(af[i], bfr[j], acc[i][j], 0, 0, 0);
        CFENCE;
        cur = (cur + 1 == 3) ? 0 : cur + 1;
    }
#undef STG2
    __syncthreads();   // drain all reads before handoff aliases staging

    // split-K handoff through LDS (aliases staging)
    float* scr2 = (float*)SMb;           // 128 x 68 f32 = 34816 B
    if (g == 1) {
#pragma unroll
        for (int i = 0; i < 4; ++i)
#pragma unroll
            for (int j = 0; j < 4; ++j)
#pragma unroll
                for (int r = 0; r < 4; ++r)
                    scr2[((wm << 6) + (i << 4) + (l4 << 2) + r)*68 + (j << 4) + l15] = acc[i][j][r];
    }
    __syncthreads();
    if (g == 1) return;
#pragma unroll
    for (int i = 0; i < 4; ++i)
#pragma unroll
        for (int j = 0; j < 4; ++j)
#pragma unroll
            for (int r = 0; r < 4; ++r)
                acc[i][j][r] += scr2[((wm << 6) + (i << 4) + (l4 << 2) + r)*68 + (j << 4) + l15];

    float bcol[4];
#pragma unroll
    for (int j = 0; j < 4; ++j) bcol[j] = bias[col0 + (j << 4) + l15];
    int rr = lane >> 2, cseg = lane & 3;
    float* scr = (float*)(SMb + 36864) + w * 1088;

#pragma unroll
    for (int i = 0; i < 4; ++i) {
        LGKM0;
#pragma unroll
        for (int j = 0; j < 4; ++j)
#pragma unroll
            for (int r = 0; r < 4; ++r)
                scr[((l4 << 2) + r)*68 + (j << 4) + l15] = acc[i][j][r] + bcol[j];
        LGKM0;
        int grow = row0 + (wm << 6) + (i << 4) + rr;
        float4 q0 = *(float4*)&scr[rr*68 + (cseg << 4) + 0];
        float4 q1 = *(float4*)&scr[rr*68 + (cseg << 4) + 4];
        float4 q2 = *(float4*)&scr[rr*68 + (cseg << 4) + 8];
        float4 q3 = *(float4*)&scr[rr*68 + (cseg << 4) + 12];
        int gcol = col0 + (cseg << 4);
        size_t roff;
        if (mode == 2) {
            int rs = (grow >> 10)*L_ + PREF + (grow & (T_-1));
            roff = (size_t)rs*D_ + gcol;
        } else {
            roff = (size_t)grow*Nc + gcol;
        }
        float4 r0 = *(const float4*)(res + roff);
        float4 r1 = *(const float4*)(res + roff + 4);
        float4 r2 = *(const float4*)(res + roff + 8);
        float4 r3 = *(const float4*)(res + roff + 12);
        q0.x += r0.x; q0.y += r0.y; q0.z += r0.z; q0.w += r0.w;
        q1.x += r1.x; q1.y += r1.y; q1.z += r1.z; q1.w += r1.w;
        q2.x += r2.x; q2.y += r2.y; q2.z += r2.z; q2.w += r2.w;
        q3.x += r3.x; q3.y += r3.y; q3.z += r3.z; q3.w += r3.w;
        size_t o = (size_t)grow*Nc + gcol;
        *(float4*)(Cout + o)      = q0;
        *(float4*)(Cout + o + 4)  = q1;
        *(float4*)(Cout + o + 8)  = q2;
        *(float4*)(Cout + o + 12) = q3;
    }
}

// ---------------- MFMA flash attention, LDS-staged, load-balanced ---------
// grid: B*H*8 blocks; each block handles TWO q-tiles (qb = 15-p, then p) so
// every block does exactly 23 tile-iterations -> uniform CU load, no tail.
__global__ __launch_bounds__(256) void attn_mfma_kernel(
    const ushort* __restrict__ qhd, const ushort* __restrict__ khd,
    const ushort* __restrict__ vt, ushort* __restrict__ attn_bf)
{
    __shared__ ushort Ks[2][64*64];
    __shared__ ushort Vs[2][64*64];
    __shared__ ushort Ps[4*16*64];

    // XCD swizzle: consecutive (b,h) stay on one XCD for KV L2 reuse
    int bid0 = blockIdx.x;
    int bid = (bid0 & 7) * (gridDim.x >> 3) + (bid0 >> 3);
    int p  = bid & 7;
    int h  = (bid >> 3) & (H_ - 1);
    int b  = bid >> 7;
    int tid = threadIdx.x, lane = tid & 63, w = tid >> 6;
    int l15 = lane & 15, lg = lane >> 4;
    int wq0 = w << 4;
    size_t bh = (size_t)(b * H_ + h);

    int srow = tid >> 3;
    int sslot = tid & 7;
    ushort* Ps_w = Ps + (w << 10);
    const float SC = 0.125f * 1.4426950408889634f;

#define STAGE_T(buf, t)                                                     \
    do { int j0s = (t) << 6;                                                \
        gl_lds16(khd + (bh * L_ + j0s + srow) * 64 + ((sslot ^ (srow & 7)) << 3),      \
                 (char*)Ks[buf] + (tid << 4));                              \
        gl_lds16(khd + (bh * L_ + j0s + 32 + srow) * 64 + ((sslot ^ ((32+srow) & 7)) << 3), \
                 (char*)Ks[buf] + ((256 + tid) << 4));                      \
        gl_lds16(vt + (bh * 64 + srow) * L_ + j0s + ((sslot ^ (srow & 7)) << 3),       \
                 (char*)Vs[buf] + (tid << 4));                              \
        gl_lds16(vt + (bh * 64 + 32 + srow) * L_ + j0s + ((sslot ^ ((32+srow) & 7)) << 3), \
                 (char*)Vs[buf] + ((256 + tid) << 4));                      \
    } while (0)

#pragma unroll
    for (int sub = 0; sub < 2; ++sub) {
        int qb = sub ? p : (15 - p);
        int i0 = PREF + (qb << 6);
        const ushort* qrow = qhd + (bh * L_ + i0 + wq0 + l15) * 64;
        bf16x8 bq0 = *(const bf16x8*)(qrow + (lg << 3));
        bf16x8 bq1 = *(const bf16x8*)(qrow + 32 + (lg << 3));

        f32x4 acc[4] = {};
        float mrun = -INFINITY;
        float lsum = 0.f;
        int qcap = i0 + wq0 + l15;

        int ntile = 4 + qb;
        STAGE_T(0, 0);
        __syncthreads();
        int cur = 0;
        for (int t = 0; t < ntile; ++t) {
            if (t + 1 < ntile) STAGE_T(cur ^ 1, t + 1);
            const ushort* Kc = Ks[cur];
            const ushort* Vc = Vs[cur];

            f32x4 s4[4];
            __builtin_amdgcn_s_setprio(1);
#pragma unroll
            for (int st = 0; st < 4; ++st) {
                int rk = (st << 4) + l15;
                bf16x8 ak0 = *(const bf16x8*)(Kc + (rk << 6) + ((lg       ^ (rk & 7)) << 3));
                bf16x8 ak1 = *(const bf16x8*)(Kc + (rk << 6) + (((4 + lg) ^ (rk & 7)) << 3));
                f32x4 z = {};
                z = __builtin_amdgcn_mfma_f32_16x16x32_bf16(ak0, bq0, z, 0, 0, 0);
                z = __builtin_amdgcn_mfma_f32_16x16x32_bf16(ak1, bq1, z, 0, 0, 0);
                s4[st] = z;
            }
            __builtin_amdgcn_s_setprio(0);

            int j0 = t << 6;
            float sv[4][4];
            bool diag = (t == ntile - 1);
            int kbq = j0 + (lg << 2);
#pragma unroll
            for (int st = 0; st < 4; ++st)
#pragma unroll
                for (int r = 0; r < 4; ++r) {
                    float s = s4[st][r] * SC;
                    if (diag && (kbq + (st << 4) + r > qcap)) s = -INFINITY;
                    sv[st][r] = s;
                }
            float bm;
            {
                float t0 = fmaxf(fmaxf(sv[0][0], sv[0][1]), fmaxf(sv[0][2], sv[0][3]));
                float t1 = fmaxf(fmaxf(sv[1][0], sv[1][1]), fmaxf(sv[1][2], sv[1][3]));
                float t2 = fmaxf(fmaxf(sv[2][0], sv[2][1]), fmaxf(sv[2][2], sv[2][3]));
                float t3 = fmaxf(fmaxf(sv[3][0], sv[3][1]), fmaxf(sv[3][2], sv[3][3]));
                bm = fmaxf(fmaxf(t0, t1), fmaxf(t2, t3));
            }
            bm = fmaxf(bm, __shfl_xor(bm, 16, 64));
            bm = fmaxf(bm, __shfl_xor(bm, 32, 64));

            float mn = fmaxf(mrun, bm);
            float cr = exp2f(mrun - mn);
            mrun = mn;
            float pe[4][4];
            float ps = 0.f;
#pragma unroll
            for (int st = 0; st < 4; ++st)
#pragma unroll
                for (int r = 0; r < 4; ++r) {
                    float e = exp2f(sv[st][r] - mn);
                    pe[st][r] = e; ps += e;
                }
            ps += __shfl_xor(ps, 16, 64);
            ps += __shfl_xor(ps, 32, 64);
            lsum = lsum * cr + ps;
#pragma unroll
            for (int su = 0; su < 4; ++su) acc[su] *= cr;

#pragma unroll
            for (int st = 0; st < 4; ++st) {
                int slot = (st << 1) + (lg >> 1);
                int sb = ((lg & 1) << 3);
#pragma unroll
                for (int rp = 0; rp < 2; ++rp) {
                    uint u = (uint)f2bf(pe[st][2*rp]) | ((uint)f2bf(pe[st][2*rp+1]) << 16);
                    *(uint*)((char*)Ps_w + l15*128 + ((slot ^ (l15 & 7)) << 4) + sb + (rp << 2)) = u;
                }
            }
            {
                bf16x8 bp0 = *(const bf16x8*)((char*)Ps_w + l15*128 + ((lg       ^ (l15 & 7)) << 4));
                bf16x8 bp1 = *(const bf16x8*)((char*)Ps_w + l15*128 + (((4 + lg) ^ (l15 & 7)) << 4));
                __builtin_amdgcn_s_setprio(1);
#pragma unroll
                for (int su = 0; su < 4; ++su) {
                    int rd = (su << 4) + l15;
                    bf16x8 av0 = *(const bf16x8*)(Vc + (rd << 6) + ((lg       ^ (rd & 7)) << 3));
                    bf16x8 av1 = *(const bf16x8*)(Vc + (rd << 6) + (((4 + lg) ^ (rd & 7)) << 3));
                    acc[su] = __builtin_amdgcn_mfma_f32_16x16x32_bf16(av0, bp0, acc[su], 0, 0, 0);
                    acc[su] = __builtin_amdgcn_mfma_f32_16x16x32_bf16(av1, bp1, acc[su], 0, 0, 0);
                }
                __builtin_amdgcn_s_setprio(0);
            }
            __syncthreads();
            cur ^= 1;
        }

        float rl = 1.0f / lsum;
        size_t orow = (size_t)b * T_ + (i0 - PREF) + wq0 + l15;
#pragma unroll
        for (int su = 0; su < 4; ++su) {
            ushort4 o4;
            o4.x = f2bf(acc[su][0] * rl);
            o4.y = f2bf(acc[su][1] * rl);
            o4.z = f2bf(acc[su][2] * rl);
            o4.w = f2bf(acc[su][3] * rl);
            *(ushort4*)(attn_bf + orow * D_ + (h << 6) + (su << 4) + (lg << 2)) = o4;
        }
        __syncthreads();   // LDS safe before next sub's staging
    }
#undef STAGE_T
}

// ---------------- launch ----------------
extern "C" void kernel_launch(void* const* d_in, const int* in_sizes, int n_in,
                              void* d_out, int out_size, void* d_ws, size_t ws_size,
                              hipStream_t stream) {
    const float* x   = (const float*)d_in[0];
    const float* mem = (const float*)d_in[1];
    const float* nmr = (const float*)d_in[2];
    const float* Wq  = (const float*)d_in[3];
    const float* bq  = (const float*)d_in[4];
    const float* Wk  = (const float*)d_in[5];
    const float* bk  = (const float*)d_in[6];
    const float* Wv  = (const float*)d_in[7];
    const float* bv  = (const float*)d_in[8];
    const float* Wo  = (const float*)d_in[9];
    const float* bo  = (const float*)d_in[10];
    const float* W1  = (const float*)d_in[11];
    const float* b1  = (const float*)d_in[12];
    const float* W2  = (const float*)d_in[13];
    const float* b2  = (const float*)d_in[14];
    const float* g1  = (const float*)d_in[15];
    const float* be1 = (const float*)d_in[16];
    const float* g2  = (const float*)d_in[17];
    const float* be2 = (const float*)d_in[18];
    float* out = (float*)d_out;

    const size_t BLD = (size_t)BL_ * D_;
    const size_t BTD = (size_t)BT_ * D_;

    float* f = (float*)d_ws;
    float* x_full = f;                         // BLD f32
    float* x2     = f + BLD;                   // BTD f32
    float* bqkv   = x2 + BTD;                  // 4096 f32 (3072 used)
    float* rtab   = bqkv + 4096;               // L_*32 f32
    ushort* bfb   = (ushort*)(rtab + (size_t)L_*32);
    ushort* xa_bf   = bfb;                     // BLD  (reused as attn_bf)
    ushort* qhd     = bfb + BLD;               // BLD  (reused as ln2_bf)
    ushort* khd     = bfb + 2*BLD;             // BLD
    ushort* vt      = bfb + 3*BLD;             // BLD
    ushort* h1_bf   = bfb + 4*BLD;             // BT_*FFN_
    ushort* wq_bf = h1_bf + (size_t)BT_*FFN_;  // Q|K|V|Wo|W1|W2 contiguous
    ushort* wk_bf = wq_bf + (size_t)D_*D_;
    ushort* wv_bf = wk_bf + (size_t)D_*D_;
    ushort* wo_bf = wv_bf + (size_t)D_*D_;
    ushort* w1_bf = wo_bf + (size_t)D_*D_;
    ushort* w2_bf = w1_bf + (size_t)D_*FFN_;
    ushort* partials = w2_bf + (size_t)FFN_*D_;   // 2*BTD bf16
    ushort* attn_bf = xa_bf;
    ushort* ln2_bf  = qhd;

    // weight prep + tables
    wtr4_kernel<<<dim3(16, 16, 4), 256, 0, stream>>>(Wq, Wk, Wv, Wo,
                                                     wq_bf, wk_bf, wv_bf, wo_bf);
    wtr_kernel<<<dim3(FFN_/64, D_/64),   256, 0, stream>>>(W1, w1_bf, D_,   FFN_);
    wtr_kernel<<<dim3(D_/64,   FFN_/64), 256, 0, stream>>>(W2, w2_bf, FFN_, D_);
    prep_kernel<<<(L_*32 + 3072 + 255)/256, 256, 0, stream>>>(rtab, bq, bk, bv, bqkv);

    ln1_concat_kernel<<<BL_, 256, 0, stream>>>(x, mem, nmr, g1, be1, x_full, xa_bf);

    // fused QKV projection (N=3072): wide 128x256 structure, 456 blocks
    gemm_wide_kernel<7><<<dim3(3072/256, BL_/128), 512, 0, stream>>>(
        xa_bf, wq_bf, bqkv, rtab, qhd, D_, D_, D_);

    // load-balanced attention: 512 blocks, 23 tiles each
    attn_mfma_kernel<<<B_*H_*8, 256, 0, stream>>>(qhd, khd, vt, attn_bf);

    // x2 = attn @ Wo + bo + x_full[strided]   (128x64 tile, in-block SK2)
    gemm_sk2_kernel<<<dim3(D_/64, BT_/128), 256, 0, stream>>>(
        attn_bf, wo_bf, bo, x_full, x2, D_, D_, D_, 2);

    ln2_kernel<<<BT_, 256, 0, stream>>>(x2, g2, be2, ln2_bf);

    // h1 = relu(xf @ W1 + b1)^2   (128x256 tile)
    gemm_wide_kernel<3><<<dim3(FFN_/256, BT_/128), 512, 0, stream>>>(
        ln2_bf, w1_bf, b1, nullptr, h1_bf, FFN_, D_, D_);

    // FFN2: 128x256 tile, z-split-K=2 -> bf16 partials, then fused reduce
    gemm_wide_kernel<4><<<dim3(D_/256, BT_/128, 2), 512, 0, stream>>>(
        h1_bf, w2_bf, nullptr, nullptr, partials, D_, FFN_, FFN_/2);
    reduce2_out_kernel<<<BT_, 256, 0, stream>>>(partials, b2, x2, out);
}

// Round 24
// 215.291 us; speedup vs baseline: 1.0384x; 1.0384x over previous
//
#include <hip/hip_runtime.h>
#include <hip/hip_bf16.h>
#include <math.h>

#define D_   1024
#define H_   16
#define DH_  64
#define FFN_ 4096
#define B_   4
#define T_   1024
#define M_   128
#define N_   64
#define PREF 192
#define L_   1216
#define BL_  (B_*L_)   // 4864
#define BT_  (B_*T_)   // 4096

typedef __attribute__((ext_vector_type(4))) float f32x4;
typedef __attribute__((ext_vector_type(8))) short bf16x8;
typedef __attribute__((ext_vector_type(8))) unsigned short u16x8;
typedef const __attribute__((address_space(1))) void gvoid_t;
typedef __attribute__((address_space(3))) void lvoid_t;

#define LGKM0 asm volatile("s_waitcnt lgkmcnt(0)" ::: "memory")
#define CFENCE asm volatile("" ::: "memory")

__device__ __forceinline__ void gl_lds16(const void* g, void* l) {
    __builtin_amdgcn_global_load_lds((gvoid_t*)g, (lvoid_t*)l, 16, 0, 0);
}

__device__ __forceinline__ ushort f2bf(float x) {
    union { __hip_bfloat16 h; ushort u; } cv;
    cv.h = __float2bfloat16(x);
    return cv.u;
}

__device__ __forceinline__ float bf2f(ushort u) {
    union { unsigned int i; float f; } cv;
    cv.i = ((unsigned int)u) << 16;
    return cv.f;
}

__device__ __forceinline__ u16x8 pack8(float4 a, float4 b) {
    u16x8 r;
    r[0]=f2bf(a.x); r[1]=f2bf(a.y); r[2]=f2bf(a.z); r[3]=f2bf(a.w);
    r[4]=f2bf(b.x); r[5]=f2bf(b.y); r[6]=f2bf(b.z); r[7]=f2bf(b.w);
    return r;
}

// ---------------- block reduce helper ----------------
__device__ __forceinline__ float block_reduce_sum256(float v, float* sbuf) {
#pragma unroll
    for (int o = 32; o > 0; o >>= 1) v += __shfl_xor(v, o, 64);
    int w = threadIdx.x >> 6;
    if ((threadIdx.x & 63) == 0) sbuf[w] = v;
    __syncthreads();
    float r = sbuf[0] + sbuf[1] + sbuf[2] + sbuf[3];
    __syncthreads();
    return r;
}

// ---------------- weight tile fp32 [K][Nc] -> bf16 W^T [Nc][K] -------------
__device__ __forceinline__ void wtr_tile(const float* __restrict__ W,
                                         ushort* __restrict__ Wt, int K, int Nc,
                                         int cblk, int kblk, float (*tl)[65])
{
    int c0 = cblk << 6, k0 = kblk << 6;
    int tid = threadIdx.x;
    int rr = tid >> 4, c4 = (tid & 15) << 2;
#pragma unroll
    for (int p = 0; p < 4; ++p) {
        int r = (p << 4) + rr;
        float4 v = *(const float4*)(W + (size_t)(k0 + r) * Nc + c0 + c4);
        tl[r][c4+0] = v.x; tl[r][c4+1] = v.y; tl[r][c4+2] = v.z; tl[r][c4+3] = v.w;
    }
    __syncthreads();
#pragma unroll
    for (int p = 0; p < 4; ++p) {
        int rT = (p << 4) + rr;
        ushort4 uv;
        uv.x = f2bf(tl[c4+0][rT]);
        uv.y = f2bf(tl[c4+1][rT]);
        uv.z = f2bf(tl[c4+2][rT]);
        uv.w = f2bf(tl[c4+3][rT]);
        *(ushort4*)(Wt + (size_t)(c0 + rT) * K + k0 + c4) = uv;
    }
}

// ---------------- merged prep: ln1+concat | 6 weight transposes | tables --
// grid layout (blocks of 256):
//   [0, BL_)            ln1_concat rows
//   [BL_, BL_+1024)     Wq/Wk/Wv/Wo transpose tiles (z = idx>>8)
//   [+1024)             W1 tiles (c = idx&63, k = idx>>6)
//   [+1024)             W2 tiles (c = idx&15, k = idx>>4)
//   [+164)              RoPE table + bias concat
__global__ __launch_bounds__(256) void prep_all_kernel(
    const float* __restrict__ x, const float* __restrict__ mem,
    const float* __restrict__ nmr, const float* __restrict__ g,
    const float* __restrict__ be,
    const float* __restrict__ Wq, const float* __restrict__ Wk,
    const float* __restrict__ Wv, const float* __restrict__ Wo,
    const float* __restrict__ W1, const float* __restrict__ W2,
    ushort* __restrict__ wq_bf, ushort* __restrict__ wk_bf,
    ushort* __restrict__ wv_bf, ushort* __restrict__ wo_bf,
    ushort* __restrict__ w1_bf, ushort* __restrict__ w2_bf,
    const float* __restrict__ bq, const float* __restrict__ bk,
    const float* __restrict__ bv,
    float* __restrict__ x_full, ushort* __restrict__ xa_bf,
    float* __restrict__ rtab, float* __restrict__ bqkv)
{
    __shared__ float tl[64][65];
    int bid = blockIdx.x;
    int tid = threadIdx.x;

    if (bid < BL_) {
        // ----- ln1 + concat -----
        float* sbuf = &tl[0][0];
        int row = bid;
        int b = row / L_, pos = row % L_;
        const float* src;
        if (pos < M_)          src = mem + ((size_t)b*M_ + pos)      * D_;
        else if (pos < M_+N_)  src = nmr + ((size_t)b*N_ + (pos-M_)) * D_;
        else                   src = x   + ((size_t)b*T_ + (pos-PREF))*D_;

        int c = tid << 2;
        float4 v = *(const float4*)(src + c);
        float s = v.x + v.y + v.z + v.w;
        s = block_reduce_sum256(s, sbuf);
        float mu = s * (1.0f / D_);
        float dx = v.x - mu, dy = v.y - mu, dz = v.z - mu, dw = v.w - mu;
        float q = dx*dx + dy*dy + dz*dz + dw*dw;
        q = block_reduce_sum256(q, sbuf);
        float inv = rsqrtf(q * (1.0f / D_) + 1e-5f);
        float4 gv = *(const float4*)(g + c);
        float4 bv4 = *(const float4*)(be + c);
        ushort4 o;
        o.x = f2bf(dx*inv*gv.x + bv4.x);
        o.y = f2bf(dy*inv*gv.y + bv4.y);
        o.z = f2bf(dz*inv*gv.z + bv4.z);
        o.w = f2bf(dw*inv*gv.w + bv4.w);
        *(float4*)(x_full + (size_t)row*D_ + c) = v;
        *(ushort4*)(xa_bf + (size_t)row*D_ + c) = o;
        return;
    }
    bid -= BL_;

    if (bid < 1024) {
        // ----- Wq/Wk/Wv/Wo transposes (D_ x D_) -----
        int z = bid >> 8, r = bid & 255;
        const float* W; ushort* T;
        switch (z) {
            case 0: W = Wq; T = wq_bf; break;
            case 1: W = Wk; T = wk_bf; break;
            case 2: W = Wv; T = wv_bf; break;
            default: W = Wo; T = wo_bf; break;
        }
        wtr_tile(W, T, D_, D_, r & 15, r >> 4, tl);
        return;
    }
    bid -= 1024;

    if (bid < 1024) {
        // ----- W1 transpose: K=D_, Nc=FFN_ (64 c-tiles x 16 k-tiles) -----
        wtr_tile(W1, w1_bf, D_, FFN_, bid & 63, bid >> 6, tl);
        return;
    }
    bid -= 1024;

    if (bid < 1024) {
        // ----- W2 transpose: K=FFN_, Nc=D_ (16 c-tiles x 64 k-tiles) -----
        wtr_tile(W2, w2_bf, FFN_, D_, bid & 15, bid >> 4, tl);
        return;
    }
    bid -= 1024;

    // ----- RoPE table + bias concat -----
    int i = bid * 256 + tid;
    if (i < L_ * 32) {
        int pos = i >> 5, idx = i & 31;
        int fi = idx & 15;
        float invf = exp2f(-(float)fi * 0.83048202372f);   // 10000^(-fi/16)
        float th = (float)pos * invf;
        rtab[i] = (idx < 16) ? cosf(th) : sinf(th);
    } else {
        int j = i - L_ * 32;
        if (j < 3072) {
            float v = (j < 1024) ? bq[j] : (j < 2048 ? bk[j - 1024] : bv[j - 2048]);
            bqkv[j] = v;
        }
    }
}

// ---------------- LayerNorm2: f32 in, bf16 out ----------------------------
__global__ __launch_bounds__(256) void ln2_kernel(
    const float* __restrict__ src, const float* __restrict__ g,
    const float* __restrict__ be, ushort* __restrict__ dst)
{
    __shared__ float sbuf[4];
    int row = blockIdx.x;
    int c = threadIdx.x << 2;
    float4 v = *(const float4*)(src + (size_t)row*D_ + c);
    float s = v.x + v.y + v.z + v.w;
    s = block_reduce_sum256(s, sbuf);
    float mu = s * (1.0f / D_);
    float dx = v.x - mu, dy = v.y - mu, dz = v.z - mu, dw = v.w - mu;
    float q = dx*dx + dy*dy + dz*dz + dw*dw;
    q = block_reduce_sum256(q, sbuf);
    float inv = rsqrtf(q * (1.0f / D_) + 1e-5f);
    float4 gv = *(const float4*)(g + c);
    float4 bv = *(const float4*)(be + c);
    ushort4 o;
    o.x = f2bf(dx*inv*gv.x + bv.x);
    o.y = f2bf(dy*inv*gv.y + bv.y);
    o.z = f2bf(dz*inv*gv.z + bv.z);
    o.w = f2bf(dw*inv*gv.w + bv.w);
    *(ushort4*)(dst + (size_t)row*D_ + c) = o;
}

// ---------------- split-K=2 reduce (bf16 partials) + bias + res -> out ----
__global__ __launch_bounds__(256) void reduce2_out_kernel(
    const ushort* __restrict__ part, const float* __restrict__ b2,
    const float* __restrict__ x2, float* __restrict__ out)
{
    int row = blockIdx.x;
    int c = threadIdx.x << 2;
    size_t o = (size_t)row * D_ + c;
    const size_t S = (size_t)BT_ * D_;
    ushort4 u0 = *(const ushort4*)(part + o);
    ushort4 u1 = *(const ushort4*)(part + S + o);
    float4 bb = *(const float4*)(b2 + c);
    float4 rv = *(const float4*)(x2 + o);
    float4 v;
    v.x = bf2f(u0.x) + bf2f(u1.x) + bb.x + rv.x;
    v.y = bf2f(u0.y) + bf2f(u1.y) + bb.y + rv.y;
    v.z = bf2f(u0.z) + bf2f(u1.z) + bb.z + rv.z;
    v.w = bf2f(u0.w) + bf2f(u1.w) + bb.w + rv.w;
    *(float4*)(out + o) = v;
}

// ---------------- 512-thr GEMM: 128x256 tile, 3-slot, 1 barrier/iter ------
// MODE 3: relu(+bias)^2 bf16 out (FFN1).
// MODE 4: bf16 partial out at Cout + z*BT_*D_, kbase = z*Klen (FFN2 split-K).
// MODE 7: fused QKV epilogue (Q/K RoPE via table, V transposed head-major).
template<int MODE>
__global__ __launch_bounds__(512) void gemm_wide_kernel(
    const ushort* __restrict__ A, const ushort* __restrict__ Bt,
    const float* __restrict__ bias, const float* __restrict__ rtab,
    void* __restrict__ Cout, int Nc, int Kstride, int Klen)
{
    __shared__ ushort SM[36864];   // 72 KB: A 3x8KB | B 3x16KB
    char* SMb = (char*)SM;

    int tid = threadIdx.x;
    int lane = tid & 63, w = tid >> 6;
    int l15 = lane & 15, l4 = lane >> 4;

    int nx = gridDim.x;
    int flat = blockIdx.y * nx + blockIdx.x;
    int cpx = (nx * gridDim.y) >> 3;
    int sz = (flat & 7) * cpx + (flat >> 3);
    int row0 = (sz / nx) << 7, col0 = (sz % nx) << 8;
    int kbase = blockIdx.z * Klen;

    int wm = w >> 2, wn = w & 3;

    f32x4 acc[4][4] = {};

    int rA = tid >> 2, scA = tid & 3;
    int lcA = (scA ^ ((rA >> 1) & 3)) << 3;
    const ushort* Ar = A + (size_t)(row0 + rA) * Kstride + kbase + lcA;
    int lcB1 = (scA ^ (((128 + rA) >> 1) & 3)) << 3;
    const ushort* Br0 = Bt + (size_t)(col0 + rA)       * Kstride + kbase + lcA;
    const ushort* Br1 = Bt + (size_t)(col0 + 128 + rA) * Kstride + kbase + lcB1;

#define STG1(bb, k0rel)                                                       \
    do {                                                                      \
        gl_lds16(Ar  + (k0rel), SMb + (bb)*8192 + (tid << 4));                \
        gl_lds16(Br0 + (k0rel), SMb + 24576 + (bb)*16384 + (tid << 4));       \
        gl_lds16(Br1 + (k0rel), SMb + 24576 + (bb)*16384 + 8192 + (tid << 4));\
    } while (0)

    int nIt = Klen >> 5;
    STG1(0, 0);
    STG1(1, 32);
    int cur = 0;
    for (int it = 0; it < nIt; ++it) {
        if (it + 1 < nIt) {
            asm volatile("s_waitcnt vmcnt(3)" ::: "memory");
        } else {
            asm volatile("s_waitcnt vmcnt(0)" ::: "memory");
        }
        __builtin_amdgcn_s_barrier();
        CFENCE;
        if (it + 2 < nIt) {
            int s2 = cur + 2; if (s2 >= 3) s2 -= 3;
            STG1(s2, (it + 2) << 5);
        }
        const ushort* As = (const ushort*)(SMb + cur*8192);
        const ushort* Bs = (const ushort*)(SMb + 24576 + cur*16384);
        bf16x8 af[4], bfr[4];
#pragma unroll
        for (int i = 0; i < 4; ++i) {
            int ra = (wm << 6) + (i << 4) + l15;
            af[i]  = *(const bf16x8*)(&As[ra*32 + ((l4 ^ ((ra >> 1) & 3)) << 3)]);
            int rb = (wn << 6) + (i << 4) + l15;
            bfr[i] = *(const bf16x8*)(&Bs[rb*32 + ((l4 ^ ((rb >> 1) & 3)) << 3)]);
        }
#pragma unroll
        for (int i = 0; i < 4; ++i)
#pragma unroll
            for (int j = 0; j < 4; ++j)
                acc[i][j] = __builtin_amdgcn_mfma_f32_16x16x32_bf16(af[i], bfr[j], acc[i][j], 0, 0, 0);
        CFENCE;
        cur = (cur + 1 == 3) ? 0 : cur + 1;
    }
#undef STG1
    __syncthreads();   // drain reads before scratch aliases staging

    float bcol[4] = {0.f, 0.f, 0.f, 0.f};
    if (MODE != 4) {
#pragma unroll
        for (int j = 0; j < 4; ++j) bcol[j] = bias[col0 + (wn << 6) + (j << 4) + l15];
    }

    float* scr = (float*)SMb + w * 1088;   // aliases staging (dead)
    int rr = lane >> 2, cseg = lane & 3;
    int colbase = col0 + (wn << 6);
    int which = colbase >> 10;                // 0 Q, 1 K, 2 V (MODE 7)
    int hh = (colbase & 1023) >> 6;           // head (MODE 7)

#pragma unroll
    for (int i = 0; i < 4; ++i) {
        LGKM0;
#pragma unroll
        for (int j = 0; j < 4; ++j)
#pragma unroll
            for (int r = 0; r < 4; ++r) {
                float v = acc[i][j][r] + bcol[j];
                if (MODE == 3) { v = fmaxf(v, 0.f); v *= v; }
                scr[((l4 << 2) + r)*68 + (j << 4) + l15] = v;
            }
        LGKM0;
        int grow = row0 + (wm << 6) + (i << 4) + rr;

        if (MODE == 7 && which == 2) {
            // V^T: lane owns d = lane; 16 contiguous pos per chunk
            int r0g = row0 + (wm << 6) + (i << 4);
            int bb = r0g / L_;
            int posb = r0g - bb * L_;              // 16-aligned, never straddles
            float4 v0, v1, v2, v3;
            v0.x = scr[ 0*68 + lane]; v0.y = scr[ 1*68 + lane];
            v0.z = scr[ 2*68 + lane]; v0.w = scr[ 3*68 + lane];
            v1.x = scr[ 4*68 + lane]; v1.y = scr[ 5*68 + lane];
            v1.z = scr[ 6*68 + lane]; v1.w = scr[ 7*68 + lane];
            v2.x = scr[ 8*68 + lane]; v2.y = scr[ 9*68 + lane];
            v2.z = scr[10*68 + lane]; v2.w = scr[11*68 + lane];
            v3.x = scr[12*68 + lane]; v3.y = scr[13*68 + lane];
            v3.z = scr[14*68 + lane]; v3.w = scr[15*68 + lane];
            ushort* O = (ushort*)Cout + 2*(size_t)BL_*D_;
            size_t base = ((size_t)(bb*H_ + hh)*64 + lane)*L_ + posb;
            *(u16x8*)(O + base)     = pack8(v0, v1);
            *(u16x8*)(O + base + 8) = pack8(v2, v3);
        } else if (MODE == 7) {
            // Q/K: lane owns one pos row, 16 cols; RoPE from table
            int bb = grow / L_;
            int pos = grow - bb * L_;
            float4 a0 = *(float4*)&scr[rr*68 + (cseg << 4) + 0];
            float4 a1 = *(float4*)&scr[rr*68 + (cseg << 4) + 4];
            float4 a2 = *(float4*)&scr[rr*68 + (cseg << 4) + 8];
            float4 a3 = *(float4*)&scr[rr*68 + (cseg << 4) + 12];
            if (cseg < 2) {
                int oseg = cseg ^ 1;
                float4 p0 = *(float4*)&scr[rr*68 + (oseg << 4) + 0];
                float4 p1 = *(float4*)&scr[rr*68 + (oseg << 4) + 4];
                float4 p2 = *(float4*)&scr[rr*68 + (oseg << 4) + 8];
                float4 p3 = *(float4*)&scr[rr*68 + (oseg << 4) + 12];
                const float* tb = rtab + pos*32;
                float4 c0 = *(const float4*)(tb + 0),  c1 = *(const float4*)(tb + 4);
                float4 c2 = *(const float4*)(tb + 8),  c3 = *(const float4*)(tb + 12);
                float4 s0 = *(const float4*)(tb + 16), s1 = *(const float4*)(tb + 20);
                float4 s2 = *(const float4*)(tb + 24), s3 = *(const float4*)(tb + 28);
                float sg = (cseg == 0) ? -1.f : 1.f;
                a0.x = a0.x*c0.x + sg*p0.x*s0.x; a0.y = a0.y*c0.y + sg*p0.y*s0.y;
                a0.z = a0.z*c0.z + sg*p0.z*s0.z; a0.w = a0.w*c0.w + sg*p0.w*s0.w;
                a1.x = a1.x*c1.x + sg*p1.x*s1.x; a1.y = a1.y*c1.y + sg*p1.y*s1.y;
                a1.z = a1.z*c1.z + sg*p1.z*s1.z; a1.w = a1.w*c1.w + sg*p1.w*s1.w;
                a2.x = a2.x*c2.x + sg*p2.x*s2.x; a2.y = a2.y*c2.y + sg*p2.y*s2.y;
                a2.z = a2.z*c2.z + sg*p2.z*s2.z; a2.w = a2.w*c2.w + sg*p2.w*s2.w;
                a3.x = a3.x*c3.x + sg*p3.x*s3.x; a3.y = a3.y*c3.y + sg*p3.y*s3.y;
                a3.z = a3.z*c3.z + sg*p3.z*s3.z; a3.w = a3.w*c3.w + sg*p3.w*s3.w;
            }
            ushort* O = (ushort*)Cout + (size_t)which * ((size_t)BL_*D_);
            size_t base = (((size_t)(bb*H_ + hh)*L_ + pos) << 6) + (cseg << 4);
            *(u16x8*)(O + base)     = pack8(a0, a1);
            *(u16x8*)(O + base + 8) = pack8(a2, a3);
        } else {
            float4 q0 = *(float4*)&scr[rr*68 + (cseg << 4) + 0];
            float4 q1 = *(float4*)&scr[rr*68 + (cseg << 4) + 4];
            float4 q2 = *(float4*)&scr[rr*68 + (cseg << 4) + 8];
            float4 q3 = *(float4*)&scr[rr*68 + (cseg << 4) + 12];
            int gcol = colbase + (cseg << 4);
            if (MODE == 3) {
                ushort* O = (ushort*)Cout;
                *(u16x8*)(O + (size_t)grow*Nc + gcol)     = pack8(q0, q1);
                *(u16x8*)(O + (size_t)grow*Nc + gcol + 8) = pack8(q2, q3);
            } else {
                // bf16 partials (halves split-K HBM traffic)
                ushort* O = (ushort*)Cout + (size_t)blockIdx.z * ((size_t)BT_ * D_);
                size_t o = (size_t)grow*Nc + gcol;
                *(u16x8*)(O + o)     = pack8(q0, q1);
                *(u16x8*)(O + o + 8) = pack8(q2, q3);
            }
        }
    }
}

// ---------------- 256-thr GEMM: 128x64 tile, in-block split-K=2 -----------
// 3-slot pipeline per group, single barrier/iter, vmcnt(6)/0.
// modes: 1 f32 +bias +res(row-major) | 2 f32 +bias +res(strided x_full)
__global__ __launch_bounds__(256) void gemm_sk2_kernel(
    const ushort* __restrict__ A, const ushort* __restrict__ Bt,
    const float* __restrict__ bias, const float* __restrict__ res,
    float* __restrict__ Cout, int Nc, int Kstride, int Klen, int mode)
{
    __shared__ ushort SM[36864];   // 72 KB
    char* SMb = (char*)SM;
    int tid = threadIdx.x;
    int lane = tid & 63, w = tid >> 6;
    int l15 = lane & 15, l4 = lane >> 4;
    int g = w >> 1, wm = w & 1;

    int nx = gridDim.x;
    int flat = blockIdx.y * nx + blockIdx.x;
    int cpx = (nx * gridDim.y) >> 3;
    int sz = (flat & 7) * cpx + (flat >> 3);
    int row0 = (sz / nx) << 7, col0 = (sz % nx) << 6;

    f32x4 acc[4][4] = {};
    const int kl = Klen >> 1;
    const int kb = g * kl;

    int gt = tid & 127;
    int rB = gt >> 2, sc = gt & 3;
    const ushort* Abase = A  + (size_t)row0 * Kstride + kb;
    const ushort* Bbase = Bt + (size_t)col0 * Kstride + kb;
    char* ALg = SMb + g * 24576;             // 3 bufs x 8KB
    char* BLg = SMb + 49152 + g * 12288;     // 3 bufs x 4KB

#define STG2(bb, k0rel)                                                       \
    do {                                                                      \
        _Pragma("unroll")                                                     \
        for (int p = 0; p < 4; ++p) {                                         \
            int rw = (p << 5) + rB; int lc = sc ^ ((rw >> 1) & 3);            \
            gl_lds16(Abase + (size_t)rw*Kstride + (k0rel) + (lc << 3),        \
                     ALg + (bb)*8192 + (p << 11) + (gt << 4));                \
        }                                                                     \
        _Pragma("unroll")                                                     \
        for (int p = 0; p < 2; ++p) {                                         \
            int rw = (p << 5) + rB; int lc = sc ^ ((rw >> 1) & 3);            \
            gl_lds16(Bbase + (size_t)rw*Kstride + (k0rel) + (lc << 3),        \
                     BLg + (bb)*4096 + (p << 11) + (gt << 4));                \
        }                                                                     \
    } while (0)

    int nIt = kl >> 5;
    STG2(0, 0);
    STG2(1, 32);
    int cur = 0;
    for (int it = 0; it < nIt; ++it) {
        if (it + 1 < nIt) {
            asm volatile("s_waitcnt vmcnt(6)" ::: "memory");
        } else {
            asm volatile("s_waitcnt vmcnt(0)" ::: "memory");
        }
        __builtin_amdgcn_s_barrier();
        CFENCE;
        if (it + 2 < nIt) {
            int s2 = cur + 2; if (s2 >= 3) s2 -= 3;
            STG2(s2, (it + 2) << 5);
        }
        const ushort* As = (const ushort*)(ALg + cur*8192);
        const ushort* Bs = (const ushort*)(BLg + cur*4096);
        bf16x8 af[4], bfr[4];
#pragma unroll
        for (int i = 0; i < 4; ++i) {
            int ra = (wm << 6) + (i << 4) + l15;
            af[i]  = *(const bf16x8*)(&As[ra*32 + ((l4 ^ ((ra >> 1) & 3)) << 3)]);
            int rb = (i << 4) + l15;
            bfr[i] = *(const bf16x8*)(&Bs[rb*32 + ((l4 ^ ((rb >> 1) & 3)) << 3)]);
        }
#pragma unroll
        for (int i = 0; i < 4; ++i)
#pragma unroll
            for (int j = 0; j < 4; ++j)
                acc[i][j] = __builtin_amdgcn_mfma_f32_16x16x32_bf16(af[i], bfr[j], acc[i][j], 0, 0, 0);
        CFENCE;
        cur = (cur + 1 == 3) ? 0 : cur + 1;
    }
#undef STG2
    __syncthreads();   // drain all reads before handoff aliases staging

    // split-K handoff through LDS (aliases staging)
    float* scr2 = (float*)SMb;           // 128 x 68 f32 = 34816 B
    if (g == 1) {
#pragma unroll
        for (int i = 0; i < 4; ++i)
#pragma unroll
            for (int j = 0; j < 4; ++j)
#pragma unroll
                for (int r = 0; r < 4; ++r)
                    scr2[((wm << 6) + (i << 4) + (l4 << 2) + r)*68 + (j << 4) + l15] = acc[i][j][r];
    }
    __syncthreads();
    if (g == 1) return;
#pragma unroll
    for (int i = 0; i < 4; ++i)
#pragma unroll
        for (int j = 0; j < 4; ++j)
#pragma unroll
            for (int r = 0; r < 4; ++r)
                acc[i][j][r] += scr2[((wm << 6) + (i << 4) + (l4 << 2) + r)*68 + (j << 4) + l15];

    float bcol[4];
#pragma unroll
    for (int j = 0; j < 4; ++j) bcol[j] = bias[col0 + (j << 4) + l15];
    int rr = lane >> 2, cseg = lane & 3;
    float* scr = (float*)(SMb + 36864) + w * 1088;

#pragma unroll
    for (int i = 0; i < 4; ++i) {
        LGKM0;
#pragma unroll
        for (int j = 0; j < 4; ++j)
#pragma unroll
            for (int r = 0; r < 4; ++r)
                scr[((l4 << 2) + r)*68 + (j << 4) + l15] = acc[i][j][r] + bcol[j];
        LGKM0;
        int grow = row0 + (wm << 6) + (i << 4) + rr;
        float4 q0 = *(float4*)&scr[rr*68 + (cseg << 4) + 0];
        float4 q1 = *(float4*)&scr[rr*68 + (cseg << 4) + 4];
        float4 q2 = *(float4*)&scr[rr*68 + (cseg << 4) + 8];
        float4 q3 = *(float4*)&scr[rr*68 + (cseg << 4) + 12];
        int gcol = col0 + (cseg << 4);
        size_t roff;
        if (mode == 2) {
            int rs = (grow >> 10)*L_ + PREF + (grow & (T_-1));
            roff = (size_t)rs*D_ + gcol;
        } else {
            roff = (size_t)grow*Nc + gcol;
        }
        float4 r0 = *(const float4*)(res + roff);
        float4 r1 = *(const float4*)(res + roff + 4);
        float4 r2 = *(const float4*)(res + roff + 8);
        float4 r3 = *(const float4*)(res + roff + 12);
        q0.x += r0.x; q0.y += r0.y; q0.z += r0.z; q0.w += r0.w;
        q1.x += r1.x; q1.y += r1.y; q1.z += r1.z; q1.w += r1.w;
        q2.x += r2.x; q2.y += r2.y; q2.z += r2.z; q2.w += r2.w;
        q3.x += r3.x; q3.y += r3.y; q3.z += r3.z; q3.w += r3.w;
        size_t o = (size_t)grow*Nc + gcol;
        *(float4*)(Cout + o)      = q0;
        *(float4*)(Cout + o + 4)  = q1;
        *(float4*)(Cout + o + 8)  = q2;
        *(float4*)(Cout + o + 12) = q3;
    }
}

// ---------------- MFMA flash attention, LDS-staged, load-balanced ---------
// grid: B*H*8 blocks; each block handles TWO q-tiles (qb = 15-p, then p) so
// every block does exactly 23 tile-iterations -> uniform CU load, no tail.
__global__ __launch_bounds__(256) void attn_mfma_kernel(
    const ushort* __restrict__ qhd, const ushort* __restrict__ khd,
    const ushort* __restrict__ vt, ushort* __restrict__ attn_bf)
{
    __shared__ ushort Ks[2][64*64];
    __shared__ ushort Vs[2][64*64];
    __shared__ ushort Ps[4*16*64];

    // XCD swizzle: consecutive (b,h) stay on one XCD for KV L2 reuse
    int bid0 = blockIdx.x;
    int bid = (bid0 & 7) * (gridDim.x >> 3) + (bid0 >> 3);
    int p  = bid & 7;
    int h  = (bid >> 3) & (H_ - 1);
    int b  = bid >> 7;
    int tid = threadIdx.x, lane = tid & 63, w = tid >> 6;
    int l15 = lane & 15, lg = lane >> 4;
    int wq0 = w << 4;
    size_t bh = (size_t)(b * H_ + h);

    int srow = tid >> 3;
    int sslot = tid & 7;
    ushort* Ps_w = Ps + (w << 10);
    const float SC = 0.125f * 1.4426950408889634f;

#define STAGE_T(buf, t)                                                     \
    do { int j0s = (t) << 6;                                                \
        gl_lds16(khd + (bh * L_ + j0s + srow) * 64 + ((sslot ^ (srow & 7)) << 3),      \
                 (char*)Ks[buf] + (tid << 4));                              \
        gl_lds16(khd + (bh * L_ + j0s + 32 + srow) * 64 + ((sslot ^ ((32+srow) & 7)) << 3), \
                 (char*)Ks[buf] + ((256 + tid) << 4));                      \
        gl_lds16(vt + (bh * 64 + srow) * L_ + j0s + ((sslot ^ (srow & 7)) << 3),       \
                 (char*)Vs[buf] + (tid << 4));                              \
        gl_lds16(vt + (bh * 64 + 32 + srow) * L_ + j0s + ((sslot ^ ((32+srow) & 7)) << 3), \
                 (char*)Vs[buf] + ((256 + tid) << 4));                      \
    } while (0)

#pragma unroll
    for (int sub = 0; sub < 2; ++sub) {
        int qb = sub ? p : (15 - p);
        int i0 = PREF + (qb << 6);
        const ushort* qrow = qhd + (bh * L_ + i0 + wq0 + l15) * 64;
        bf16x8 bq0 = *(const bf16x8*)(qrow + (lg << 3));
        bf16x8 bq1 = *(const bf16x8*)(qrow + 32 + (lg << 3));

        f32x4 acc[4] = {};
        float mrun = -INFINITY;
        float lsum = 0.f;
        int qcap = i0 + wq0 + l15;

        int ntile = 4 + qb;
        STAGE_T(0, 0);
        __syncthreads();
        int cur = 0;
        for (int t = 0; t < ntile; ++t) {
            if (t + 1 < ntile) STAGE_T(cur ^ 1, t + 1);
            const ushort* Kc = Ks[cur];
            const ushort* Vc = Vs[cur];

            f32x4 s4[4];
            __builtin_amdgcn_s_setprio(1);
#pragma unroll
            for (int st = 0; st < 4; ++st) {
                int rk = (st << 4) + l15;
                bf16x8 ak0 = *(const bf16x8*)(Kc + (rk << 6) + ((lg       ^ (rk & 7)) << 3));
                bf16x8 ak1 = *(const bf16x8*)(Kc + (rk << 6) + (((4 + lg) ^ (rk & 7)) << 3));
                f32x4 z = {};
                z = __builtin_amdgcn_mfma_f32_16x16x32_bf16(ak0, bq0, z, 0, 0, 0);
                z = __builtin_amdgcn_mfma_f32_16x16x32_bf16(ak1, bq1, z, 0, 0, 0);
                s4[st] = z;
            }
            __builtin_amdgcn_s_setprio(0);

            int j0 = t << 6;
            float sv[4][4];
            bool diag = (t == ntile - 1);
            int kbq = j0 + (lg << 2);
#pragma unroll
            for (int st = 0; st < 4; ++st)
#pragma unroll
                for (int r = 0; r < 4; ++r) {
                    float s = s4[st][r] * SC;
                    if (diag && (kbq + (st << 4) + r > qcap)) s = -INFINITY;
                    sv[st][r] = s;
                }
            float bm;
            {
                float t0 = fmaxf(fmaxf(sv[0][0], sv[0][1]), fmaxf(sv[0][2], sv[0][3]));
                float t1 = fmaxf(fmaxf(sv[1][0], sv[1][1]), fmaxf(sv[1][2], sv[1][3]));
                float t2 = fmaxf(fmaxf(sv[2][0], sv[2][1]), fmaxf(sv[2][2], sv[2][3]));
                float t3 = fmaxf(fmaxf(sv[3][0], sv[3][1]), fmaxf(sv[3][2], sv[3][3]));
                bm = fmaxf(fmaxf(t0, t1), fmaxf(t2, t3));
            }
            bm = fmaxf(bm, __shfl_xor(bm, 16, 64));
            bm = fmaxf(bm, __shfl_xor(bm, 32, 64));

            float mn = fmaxf(mrun, bm);
            float cr = exp2f(mrun - mn);
            mrun = mn;
            float pe[4][4];
            float ps = 0.f;
#pragma unroll
            for (int st = 0; st < 4; ++st)
#pragma unroll
                for (int r = 0; r < 4; ++r) {
                    float e = exp2f(sv[st][r] - mn);
                    pe[st][r] = e; ps += e;
                }
            ps += __shfl_xor(ps, 16, 64);
            ps += __shfl_xor(ps, 32, 64);
            lsum = lsum * cr + ps;
#pragma unroll
            for (int su = 0; su < 4; ++su) acc[su] *= cr;

#pragma unroll
            for (int st = 0; st < 4; ++st) {
                int slot = (st << 1) + (lg >> 1);
                int sb = ((lg & 1) << 3);
#pragma unroll
                for (int rp = 0; rp < 2; ++rp) {
                    uint u = (uint)f2bf(pe[st][2*rp]) | ((uint)f2bf(pe[st][2*rp+1]) << 16);
                    *(uint*)((char*)Ps_w + l15*128 + ((slot ^ (l15 & 7)) << 4) + sb + (rp << 2)) = u;
                }
            }
            {
                bf16x8 bp0 = *(const bf16x8*)((char*)Ps_w + l15*128 + ((lg       ^ (l15 & 7)) << 4));
                bf16x8 bp1 = *(const bf16x8*)((char*)Ps_w + l15*128 + (((4 + lg) ^ (l15 & 7)) << 4));
                __builtin_amdgcn_s_setprio(1);
#pragma unroll
                for (int su = 0; su < 4; ++su) {
                    int rd = (su << 4) + l15;
                    bf16x8 av0 = *(const bf16x8*)(Vc + (rd << 6) + ((lg       ^ (rd & 7)) << 3));
                    bf16x8 av1 = *(const bf16x8*)(Vc + (rd << 6) + (((4 + lg) ^ (rd & 7)) << 3));
                    acc[su] = __builtin_amdgcn_mfma_f32_16x16x32_bf16(av0, bp0, acc[su], 0, 0, 0);
                    acc[su] = __builtin_amdgcn_mfma_f32_16x16x32_bf16(av1, bp1, acc[su], 0, 0, 0);
                }
                __builtin_amdgcn_s_setprio(0);
            }
            __syncthreads();
            cur ^= 1;
        }

        float rl = 1.0f / lsum;
        size_t orow = (size_t)b * T_ + (i0 - PREF) + wq0 + l15;
#pragma unroll
        for (int su = 0; su < 4; ++su) {
            ushort4 o4;
            o4.x = f2bf(acc[su][0] * rl);
            o4.y = f2bf(acc[su][1] * rl);
            o4.z = f2bf(acc[su][2] * rl);
            o4.w = f2bf(acc[su][3] * rl);
            *(ushort4*)(attn_bf + orow * D_ + (h << 6) + (su << 4) + (lg << 2)) = o4;
        }
        __syncthreads();   // LDS safe before next sub's staging
    }
#undef STAGE_T
}

// ---------------- launch ----------------
extern "C" void kernel_launch(void* const* d_in, const int* in_sizes, int n_in,
                              void* d_out, int out_size, void* d_ws, size_t ws_size,
                              hipStream_t stream) {
    const float* x   = (const float*)d_in[0];
    const float* mem = (const float*)d_in[1];
    const float* nmr = (const float*)d_in[2];
    const float* Wq  = (const float*)d_in[3];
    const float* bq  = (const float*)d_in[4];
    const float* Wk  = (const float*)d_in[5];
    const float* bk  = (const float*)d_in[6];
    const float* Wv  = (const float*)d_in[7];
    const float* bv  = (const float*)d_in[8];
    const float* Wo  = (const float*)d_in[9];
    const float* bo  = (const float*)d_in[10];
    const float* W1  = (const float*)d_in[11];
    const float* b1  = (const float*)d_in[12];
    const float* W2  = (const float*)d_in[13];
    const float* b2  = (const float*)d_in[14];
    const float* g1  = (const float*)d_in[15];
    const float* be1 = (const float*)d_in[16];
    const float* g2  = (const float*)d_in[17];
    const float* be2 = (const float*)d_in[18];
    float* out = (float*)d_out;

    const size_t BLD = (size_t)BL_ * D_;
    const size_t BTD = (size_t)BT_ * D_;

    float* f = (float*)d_ws;
    float* x_full = f;                         // BLD f32
    float* x2     = f + BLD;                   // BTD f32
    float* bqkv   = x2 + BTD;                  // 4096 f32 (3072 used)
    float* rtab   = bqkv + 4096;               // L_*32 f32
    ushort* bfb   = (ushort*)(rtab + (size_t)L_*32);
    ushort* xa_bf   = bfb;                     // BLD  (reused as attn_bf)
    ushort* qhd     = bfb + BLD;               // BLD  (reused as ln2_bf)
    ushort* khd     = bfb + 2*BLD;             // BLD
    ushort* vt      = bfb + 3*BLD;             // BLD
    ushort* h1_bf   = bfb + 4*BLD;             // BT_*FFN_
    ushort* wq_bf = h1_bf + (size_t)BT_*FFN_;  // Q|K|V|Wo|W1|W2 contiguous
    ushort* wk_bf = wq_bf + (size_t)D_*D_;
    ushort* wv_bf = wk_bf + (size_t)D_*D_;
    ushort* wo_bf = wv_bf + (size_t)D_*D_;
    ushort* w1_bf = wo_bf + (size_t)D_*D_;
    ushort* w2_bf = w1_bf + (size_t)D_*FFN_;
    ushort* partials = w2_bf + (size_t)FFN_*D_;   // 2*BTD bf16
    ushort* attn_bf = xa_bf;
    ushort* ln2_bf  = qhd;

    // merged prep: ln1+concat (4864) | 6 weight transposes (3072) | tables (164)
    prep_all_kernel<<<BL_ + 3*1024 + 164, 256, 0, stream>>>(
        x, mem, nmr, g1, be1,
        Wq, Wk, Wv, Wo, W1, W2,
        wq_bf, wk_bf, wv_bf, wo_bf, w1_bf, w2_bf,
        bq, bk, bv,
        x_full, xa_bf, rtab, bqkv);

    // fused QKV projection (N=3072): wide 128x256 structure, 456 blocks
    gemm_wide_kernel<7><<<dim3(3072/256, BL_/128), 512, 0, stream>>>(
        xa_bf, wq_bf, bqkv, rtab, qhd, D_, D_, D_);

    // load-balanced attention: 512 blocks, 23 tiles each
    attn_mfma_kernel<<<B_*H_*8, 256, 0, stream>>>(qhd, khd, vt, attn_bf);

    // x2 = attn @ Wo + bo + x_full[strided]   (128x64 tile, in-block SK2)
    gemm_sk2_kernel<<<dim3(D_/64, BT_/128), 256, 0, stream>>>(
        attn_bf, wo_bf, bo, x_full, x2, D_, D_, D_, 2);

    ln2_kernel<<<BT_, 256, 0, stream>>>(x2, g2, be2, ln2_bf);

    // h1 = relu(xf @ W1 + b1)^2   (128x256 tile)
    gemm_wide_kernel<3><<<dim3(FFN_/256, BT_/128), 512, 0, stream>>>(
        ln2_bf, w1_bf, b1, nullptr, h1_bf, FFN_, D_, D_);

    // FFN2: 128x256 tile, z-split-K=2 -> bf16 partials, then fused reduce
    gemm_wide_kernel<4><<<dim3(D_/256, BT_/128, 2), 512, 0, stream>>>(
        h1_bf, w2_bf, nullptr, nullptr, partials, D_, FFN_, FFN_/2);
    reduce2_out_kernel<<<BT_, 256, 0, stream>>>(partials, b2, x2, out);
}